// Round 1
// baseline (393.516 us; speedup 1.0000x reference)
//
#include <hip/hip_runtime.h>
#include <math.h>

#define F_IN 256
#define F_OUT 64
#define NEG_SLOPE 0.01f

// ---------------------------------------------------------------------------
// K0: transpose W1 (64x256 -> k-major 256x64), W2 (64x64 -> j-major 64x64),
//     and histogram of dst (fused: all tiny vs E loop).
// ---------------------------------------------------------------------------
__global__ void prep_hist_kernel(const float* __restrict__ W1,
                                 const float* __restrict__ W2,
                                 const int* __restrict__ dst,
                                 float* __restrict__ w1t,
                                 float* __restrict__ w2t,
                                 int* __restrict__ cnt, int E)
{
    int idx = blockIdx.x * blockDim.x + threadIdx.x;
    if (idx < F_IN * F_OUT) {              // w1t[k*64+f] = W1[f*256+k]
        int k = idx >> 6, f = idx & 63;
        w1t[idx] = W1[f * F_IN + k];
    }
    if (idx < F_OUT * F_OUT) {             // w2t[j*64+f] = W2[f*64+j]
        int j = idx >> 6, f = idx & 63;
        w2t[idx] = W2[f * F_OUT + j];
    }
    if (idx < E) atomicAdd(&cnt[dst[idx]], 1);
}

// ---------------------------------------------------------------------------
// K1: h = relu(relu(x@W1^T)@W2^T); s_dst = h@a[:64]; s_src = h@a[64:]
// One wave per 64 nodes; lane = node. Weight loads are wave-uniform -> SGPR.
// Each lane keeps full 64-wide z and h accumulators in VGPRs.
// ---------------------------------------------------------------------------
__global__ __launch_bounds__(64)
void node_mlp_kernel(const float* __restrict__ x,
                     const float* __restrict__ w1t,
                     const float* __restrict__ w2t,
                     const float* __restrict__ a,
                     float* __restrict__ h,
                     float* __restrict__ sdst,
                     float* __restrict__ ssrc, int N)
{
    const int lane = threadIdx.x;
    const int node = blockIdx.x * 64 + lane;
    const int nc = node < N ? node : N - 1;
    const float4* __restrict__ xrow = (const float4*)(x + (size_t)nc * F_IN);

    float z[F_OUT];
#pragma unroll
    for (int f = 0; f < F_OUT; f++) z[f] = 0.f;

    // GEMM1: z[f] += x[k] * W1[f][k]   (w1t is k-major)
    for (int k4 = 0; k4 < F_IN / 4; k4++) {
        float4 xv = xrow[k4];
        float xs[4] = {xv.x, xv.y, xv.z, xv.w};
#pragma unroll
        for (int kk = 0; kk < 4; kk++) {
            const float4* __restrict__ wrow =
                (const float4*)(w1t + (k4 * 4 + kk) * F_OUT);
            float xk = xs[kk];
#pragma unroll
            for (int fq = 0; fq < 16; fq++) {
                float4 w = wrow[fq];
                z[4 * fq + 0] = fmaf(xk, w.x, z[4 * fq + 0]);
                z[4 * fq + 1] = fmaf(xk, w.y, z[4 * fq + 1]);
                z[4 * fq + 2] = fmaf(xk, w.z, z[4 * fq + 2]);
                z[4 * fq + 3] = fmaf(xk, w.w, z[4 * fq + 3]);
            }
        }
    }
#pragma unroll
    for (int f = 0; f < F_OUT; f++) z[f] = z[f] > 0.f ? z[f] : 0.f;

    // GEMM2: h[f] += z[j] * W2[f][j]   (w2t is j-major); fully unrolled so
    // z[j] stays a static register index.
    float hv[F_OUT];
#pragma unroll
    for (int f = 0; f < F_OUT; f++) hv[f] = 0.f;
#pragma unroll
    for (int j = 0; j < F_OUT; j++) {
        float zj = z[j];
        const float4* __restrict__ wrow = (const float4*)(w2t + j * F_OUT);
#pragma unroll
        for (int fq = 0; fq < 16; fq++) {
            float4 w = wrow[fq];
            hv[4 * fq + 0] = fmaf(zj, w.x, hv[4 * fq + 0]);
            hv[4 * fq + 1] = fmaf(zj, w.y, hv[4 * fq + 1]);
            hv[4 * fq + 2] = fmaf(zj, w.z, hv[4 * fq + 2]);
            hv[4 * fq + 3] = fmaf(zj, w.w, hv[4 * fq + 3]);
        }
    }

    float sd = 0.f, ss = 0.f;
#pragma unroll
    for (int f = 0; f < F_OUT; f++) {
        float hf = hv[f] > 0.f ? hv[f] : 0.f;
        hv[f] = hf;
        sd = fmaf(hf, a[f], sd);
        ss = fmaf(hf, a[F_OUT + f], ss);
    }

    if (node < N) {
        float4* hrow = (float4*)(h + (size_t)node * F_OUT);
#pragma unroll
        for (int fq = 0; fq < 16; fq++)
            hrow[fq] = make_float4(hv[4 * fq + 0], hv[4 * fq + 1],
                                   hv[4 * fq + 2], hv[4 * fq + 3]);
        sdst[node] = sd;
        ssrc[node] = ss;
    }
}

// ---------------------------------------------------------------------------
// K2: exclusive scan of cnt -> offs. Single block, 1024 threads (16 waves).
// ---------------------------------------------------------------------------
__global__ __launch_bounds__(1024)
void scan_kernel(const int* __restrict__ cnt, int* __restrict__ offs, int N)
{
    __shared__ int wsum[16];
    const int tid = threadIdx.x;
    const int lane = tid & 63;
    const int wid = tid >> 6;
    int carry = 0;
    for (int base = 0; base < N; base += 1024) {
        int i = base + tid;
        int v = (i < N) ? cnt[i] : 0;
        int s = v;  // inclusive wave scan
#pragma unroll
        for (int d = 1; d < 64; d <<= 1) {
            int t = __shfl_up(s, d);
            if (lane >= d) s += t;
        }
        if (lane == 63) wsum[wid] = s;
        __syncthreads();
        if (wid == 0 && lane < 16) {
            int ws = wsum[lane];
#pragma unroll
            for (int d = 1; d < 16; d <<= 1) {
                int t = __shfl_up(ws, d);
                if (lane >= d) ws += t;
            }
            wsum[lane] = ws;
        }
        __syncthreads();
        int wprev = (wid == 0) ? 0 : wsum[wid - 1];
        if (i < N) offs[i] = carry + wprev + (s - v);
        carry += wsum[15];
        __syncthreads();  // protect wsum before next iteration
    }
}

// ---------------------------------------------------------------------------
// K3: scatter edges into dst-sorted order (counting sort payload = src).
// ---------------------------------------------------------------------------
__global__ void scatter_kernel(const int* __restrict__ src,
                               const int* __restrict__ dst,
                               const int* __restrict__ offs,
                               int* __restrict__ cursor,
                               int* __restrict__ ssorted, int E)
{
    int i = blockIdx.x * blockDim.x + threadIdx.x;
    if (i < E) {
        int d = dst[i];
        int r = atomicAdd(&cursor[d], 1);
        ssorted[offs[d] + r] = src[i];
    }
}

// ---------------------------------------------------------------------------
// K4: per-dst-node online-softmax aggregation. One wave per node; lane = f.
// Chunks of <=64 edges: lanes-over-edges for scores, then lanes-over-features
// for the weighted h accumulation (wave-synchronous LDS handoff).
// ---------------------------------------------------------------------------
__global__ __launch_bounds__(256)
void aggregate_kernel(const float* __restrict__ h,
                      const float* __restrict__ sdst,
                      const float* __restrict__ ssrc,
                      const int* __restrict__ offs,
                      const int* __restrict__ cnt,
                      const int* __restrict__ ssorted,
                      float* __restrict__ out, int N)
{
    __shared__ float w_sh[4][64];
    __shared__ int s_sh[4][64];
    const int lane = threadIdx.x & 63;
    const int wid = threadIdx.x >> 6;
    const int wave = blockIdx.x * 4 + wid;
    const int nwaves = gridDim.x * 4;

    for (int d = wave; d < N; d += nwaves) {
        const int off = offs[d];
        const int deg = cnt[d];
        const float sdd = sdst[d];
        float M = -INFINITY, S = 0.f, res = 0.f;

        for (int cb = 0; cb < deg; cb += 64) {
            int ce = min(64, deg - cb);
            float score = -INFINITY;
            int s = 0;
            if (lane < ce) {
                s = ssorted[off + cb + lane];
                float sc = sdd + ssrc[s];
                score = sc > 0.f ? sc : NEG_SLOPE * sc;
            }
            float mc = score;  // chunk max
#pragma unroll
            for (int dd = 32; dd > 0; dd >>= 1)
                mc = fmaxf(mc, __shfl_xor(mc, dd));
            float newM = fmaxf(M, mc);
            float scale = __expf(M - newM);  // exp(-inf)=0 on first chunk
            float w = (lane < ce) ? __expf(score - newM) : 0.f;
            w_sh[wid][lane] = w;
            s_sh[wid][lane] = s;
            float csum = w;
#pragma unroll
            for (int dd = 32; dd > 0; dd >>= 1)
                csum += __shfl_xor(csum, dd);
            res *= scale;
            S = S * scale + csum;
            __builtin_amdgcn_wave_barrier();
            for (int e = 0; e < ce; e++) {
                float we = w_sh[wid][e];
                int se = s_sh[wid][e];
                res = fmaf(we, h[(size_t)se * F_OUT + lane], res);
            }
            __builtin_amdgcn_wave_barrier();
            M = newM;
        }

        float hf = h[(size_t)d * F_OUT + lane];
        float r = (S > 0.f) ? (hf - res / S) : hf;
        out[(size_t)d * F_OUT + lane] = r > 0.f ? r : 0.f;
    }
}

// ---------------------------------------------------------------------------
extern "C" void kernel_launch(void* const* d_in, const int* in_sizes, int n_in,
                              void* d_out, int out_size, void* d_ws,
                              size_t ws_size, hipStream_t stream)
{
    const float* x  = (const float*)d_in[0];
    const float* W1 = (const float*)d_in[1];
    const float* W2 = (const float*)d_in[2];
    const float* a  = (const float*)d_in[3];
    const int* src  = (const int*)d_in[4];
    const int* dst  = (const int*)d_in[5];
    const int N = in_sizes[0] / F_IN;   // 50000
    const int E = in_sizes[4];          // 800000

    float* ws      = (float*)d_ws;
    float* h       = ws;                          // N*64
    float* sdst    = h + (size_t)N * F_OUT;       // N
    float* ssrc    = sdst + N;                    // N
    float* w1t     = ssrc + N;                    // 16384
    float* w2t     = w1t + F_IN * F_OUT;          // 4096
    int*   cnt     = (int*)(w2t + F_OUT * F_OUT); // N
    int*   cursor  = cnt + N;                     // N (contiguous with cnt)
    int*   offs    = cursor + N;                  // N
    int*   ssorted = offs + N;                    // E

    // zero cnt + cursor (ws is re-poisoned 0xAA before every call)
    hipMemsetAsync(cnt, 0, sizeof(int) * 2 * (size_t)N, stream);

    const int blocksE = (E + 255) / 256;
    prep_hist_kernel<<<blocksE, 256, 0, stream>>>(W1, W2, dst, w1t, w2t, cnt, E);
    node_mlp_kernel<<<(N + 63) / 64, 64, 0, stream>>>(x, w1t, w2t, a, h, sdst,
                                                      ssrc, N);
    scan_kernel<<<1, 1024, 0, stream>>>(cnt, offs, N);
    scatter_kernel<<<blocksE, 256, 0, stream>>>(src, dst, offs, cursor,
                                                ssorted, E);
    aggregate_kernel<<<2048, 256, 0, stream>>>(h, sdst, ssrc, offs, cnt,
                                               ssorted, (float*)d_out, N);
}

// Round 2
// 267.092 us; speedup vs baseline: 1.4733x; 1.4733x over previous
//
#include <hip/hip_runtime.h>
#include <math.h>

#define F_IN 256
#define F_OUT 64
#define NEG_SLOPE 0.01f

// ---------------------------------------------------------------------------
// K0: transpose W1 (64x256 -> k-major 256x64), W2 (64x64 -> j-major 64x64),
//     and histogram of dst.
// ---------------------------------------------------------------------------
__global__ void prep_hist_kernel(const float* __restrict__ W1,
                                 const float* __restrict__ W2,
                                 const int* __restrict__ dst,
                                 float* __restrict__ w1t,
                                 float* __restrict__ w2t,
                                 int* __restrict__ cnt, int E)
{
    int idx = blockIdx.x * blockDim.x + threadIdx.x;
    if (idx < F_IN * F_OUT) {              // w1t[k*64+f] = W1[f*256+k]
        int k = idx >> 6, f = idx & 63;
        w1t[idx] = W1[f * F_IN + k];
    }
    if (idx < F_OUT * F_OUT) {             // w2t[j*64+f] = W2[f*64+j]
        int j = idx >> 6, f = idx & 63;
        w2t[idx] = W2[f * F_OUT + j];
    }
    if (idx < E) atomicAdd(&cnt[dst[idx]], 1);
}

// ---------------------------------------------------------------------------
// K1: fused MLP. Block = 256 threads = 64 nodes (lane) x 4 feature-quarters
// (wave wq). Each thread holds only 16 accumulators -> no spill (R1 lesson:
// 128 accs/thread spilled to scratch, VGPR=68, 126us). Weight loads are
// wave-uniform (readfirstlane on wq) -> scalar path. z round-trips through
// padded LDS; h stored coalesced via LDS transpose.
// ---------------------------------------------------------------------------
__global__ __launch_bounds__(256)
void mlp_kernel(const float* __restrict__ x,
                const float* __restrict__ w1t,
                const float* __restrict__ w2t,
                const float* __restrict__ a,
                float* __restrict__ h,
                float* __restrict__ sdst,
                float* __restrict__ ssrc, int N)
{
    __shared__ float zh[64][65];   // z tile, then reused for h tile
    __shared__ float sred[8][64];
    const int tid = threadIdx.x;
    const int lane = tid & 63;
    const int wq = __builtin_amdgcn_readfirstlane(tid >> 6);  // 0..3
    const int node0 = blockIdx.x * 64;
    const int nc = min(node0 + lane, N - 1);
    const float4* __restrict__ xrow = (const float4*)(x + (size_t)nc * F_IN);

    // ---- GEMM1: z[wq*16+f] = sum_k x[k] * W1[f][k] ----
    float acc[16];
#pragma unroll
    for (int f = 0; f < 16; f++) acc[f] = 0.f;
    const float* __restrict__ w1p = w1t + wq * 16;
    for (int k4 = 0; k4 < F_IN / 4; k4++) {
        float4 xv = xrow[k4];
        float xs[4] = {xv.x, xv.y, xv.z, xv.w};
#pragma unroll
        for (int kk = 0; kk < 4; kk++) {
            const float4* __restrict__ wrow =
                (const float4*)(w1p + (k4 * 4 + kk) * F_OUT);
            float xk = xs[kk];
#pragma unroll
            for (int fq = 0; fq < 4; fq++) {
                float4 w = wrow[fq];
                acc[4 * fq + 0] = fmaf(xk, w.x, acc[4 * fq + 0]);
                acc[4 * fq + 1] = fmaf(xk, w.y, acc[4 * fq + 1]);
                acc[4 * fq + 2] = fmaf(xk, w.z, acc[4 * fq + 2]);
                acc[4 * fq + 3] = fmaf(xk, w.w, acc[4 * fq + 3]);
            }
        }
    }
#pragma unroll
    for (int f = 0; f < 16; f++) zh[lane][wq * 16 + f] = fmaxf(acc[f], 0.f);
    __syncthreads();

    // ---- GEMM2: h[wq*16+f] = sum_j z[j] * W2[f][j] ----
    float hacc[16];
#pragma unroll
    for (int f = 0; f < 16; f++) hacc[f] = 0.f;
    const float* __restrict__ w2p = w2t + wq * 16;
#pragma unroll 8
    for (int j = 0; j < F_OUT; j++) {
        float zj = zh[lane][j];           // row=lane, col uniform: conflict-free
        const float4* __restrict__ wrow = (const float4*)(w2p + j * F_OUT);
#pragma unroll
        for (int fq = 0; fq < 4; fq++) {
            float4 w = wrow[fq];
            hacc[4 * fq + 0] = fmaf(zj, w.x, hacc[4 * fq + 0]);
            hacc[4 * fq + 1] = fmaf(zj, w.y, hacc[4 * fq + 1]);
            hacc[4 * fq + 2] = fmaf(zj, w.z, hacc[4 * fq + 2]);
            hacc[4 * fq + 3] = fmaf(zj, w.w, hacc[4 * fq + 3]);
        }
    }
    __syncthreads();   // all waves done reading zh before reuse

    float sd = 0.f, ss = 0.f;
#pragma unroll
    for (int f = 0; f < 16; f++) {
        float hf = fmaxf(hacc[f], 0.f);
        zh[lane][wq * 16 + f] = hf;
        sd = fmaf(hf, a[wq * 16 + f], sd);
        ss = fmaf(hf, a[F_OUT + wq * 16 + f], ss);
    }
    sred[wq][lane] = sd;
    sred[4 + wq][lane] = ss;
    __syncthreads();

    if (tid < 64) {
        int node = node0 + lane;
        if (node < N) {
            sdst[node] = sred[0][lane] + sred[1][lane] + sred[2][lane] + sred[3][lane];
            ssrc[node] = sred[4][lane] + sred[5][lane] + sred[6][lane] + sred[7][lane];
        }
    }
    // coalesced h store: 1024 float4s per 64x64 tile, 4 per thread
#pragma unroll
    for (int i = 0; i < 4; i++) {
        int idx = tid + 256 * i;
        int nn = idx >> 4;                 // node within tile
        int fc = (idx & 15) << 2;          // feature col (x4)
        if (node0 + nn < N) {
            float4 v = make_float4(zh[nn][fc], zh[nn][fc + 1],
                                   zh[nn][fc + 2], zh[nn][fc + 3]);
            *(float4*)(h + (size_t)(node0 + nn) * F_OUT + fc) = v;
        }
    }
}

// ---------------------------------------------------------------------------
// K2: exclusive scan, single block, 4 elements/thread (13 serial iterations).
// ---------------------------------------------------------------------------
__global__ __launch_bounds__(1024)
void scan_kernel(const int* __restrict__ cnt, int* __restrict__ offs, int N)
{
    __shared__ int wsum[16];
    const int tid = threadIdx.x;
    const int lane = tid & 63;
    const int wid = tid >> 6;
    int carry = 0;
    for (int base = 0; base < N; base += 4096) {
        int i0 = base + tid * 4;
        int v0 = 0, v1 = 0, v2 = 0, v3 = 0;
        if (i0 + 3 < N) {
            int4 v = *(const int4*)(cnt + i0);
            v0 = v.x; v1 = v.y; v2 = v.z; v3 = v.w;
        } else {
            if (i0 < N)     v0 = cnt[i0];
            if (i0 + 1 < N) v1 = cnt[i0 + 1];
            if (i0 + 2 < N) v2 = cnt[i0 + 2];
            if (i0 + 3 < N) v3 = cnt[i0 + 3];
        }
        int tsum = v0 + v1 + v2 + v3;
        int s = tsum;
#pragma unroll
        for (int d = 1; d < 64; d <<= 1) {
            int t = __shfl_up(s, d);
            if (lane >= d) s += t;
        }
        if (lane == 63) wsum[wid] = s;
        __syncthreads();
        if (wid == 0 && lane < 16) {
            int w = wsum[lane];
#pragma unroll
            for (int d = 1; d < 16; d <<= 1) {
                int t = __shfl_up(w, d);
                if (lane >= d) w += t;
            }
            wsum[lane] = w;
        }
        __syncthreads();
        int excl = carry + (wid ? wsum[wid - 1] : 0) + (s - tsum);
        if (i0 < N)     offs[i0]     = excl;
        if (i0 + 1 < N) offs[i0 + 1] = excl + v0;
        if (i0 + 2 < N) offs[i0 + 2] = excl + v0 + v1;
        if (i0 + 3 < N) offs[i0 + 3] = excl + v0 + v1 + v2;
        carry += wsum[15];
        __syncthreads();
    }
}

// ---------------------------------------------------------------------------
// K3: scatter edges into dst-sorted order.
// ---------------------------------------------------------------------------
__global__ void scatter_kernel(const int* __restrict__ src,
                               const int* __restrict__ dst,
                               const int* __restrict__ offs,
                               int* __restrict__ cursor,
                               int* __restrict__ ssorted, int E)
{
    int i = blockIdx.x * blockDim.x + threadIdx.x;
    if (i < E) {
        int d = dst[i];
        int r = atomicAdd(&cursor[d], 1);
        ssorted[offs[d] + r] = src[i];
    }
}

// ---------------------------------------------------------------------------
// K4: per-dst-node online-softmax aggregation. One wave per node; lane = f.
// ---------------------------------------------------------------------------
__global__ __launch_bounds__(256)
void aggregate_kernel(const float* __restrict__ h,
                      const float* __restrict__ sdst,
                      const float* __restrict__ ssrc,
                      const int* __restrict__ offs,
                      const int* __restrict__ cnt,
                      const int* __restrict__ ssorted,
                      float* __restrict__ out, int N)
{
    __shared__ float w_sh[4][64];
    __shared__ int s_sh[4][64];
    const int lane = threadIdx.x & 63;
    const int wid = threadIdx.x >> 6;
    const int d = blockIdx.x * 4 + wid;
    if (d >= N) return;

    const int off = offs[d];
    const int deg = cnt[d];
    const float sdd = sdst[d];
    float M = -INFINITY, S = 0.f, res = 0.f;

    for (int cb = 0; cb < deg; cb += 64) {
        int ce = min(64, deg - cb);
        float score = -INFINITY;
        int s = 0;
        if (lane < ce) {
            s = ssorted[off + cb + lane];
            float sc = sdd + ssrc[s];
            score = sc > 0.f ? sc : NEG_SLOPE * sc;
        }
        float mc = score;
#pragma unroll
        for (int dd = 32; dd > 0; dd >>= 1)
            mc = fmaxf(mc, __shfl_xor(mc, dd));
        float newM = fmaxf(M, mc);
        float scale = __expf(M - newM);
        float w = (lane < ce) ? __expf(score - newM) : 0.f;
        w_sh[wid][lane] = w;
        s_sh[wid][lane] = s;
        float csum = w;
#pragma unroll
        for (int dd = 32; dd > 0; dd >>= 1)
            csum += __shfl_xor(csum, dd);
        res *= scale;
        S = S * scale + csum;
        __builtin_amdgcn_wave_barrier();
        for (int e = 0; e < ce; e++) {
            float we = w_sh[wid][e];
            int se = s_sh[wid][e];
            res = fmaf(we, h[(size_t)se * F_OUT + lane], res);
        }
        __builtin_amdgcn_wave_barrier();
        M = newM;
    }

    float hf = h[(size_t)d * F_OUT + lane];
    float r = (S > 0.f) ? (hf - res / S) : hf;
    out[(size_t)d * F_OUT + lane] = r > 0.f ? r : 0.f;
}

// ---------------------------------------------------------------------------
extern "C" void kernel_launch(void* const* d_in, const int* in_sizes, int n_in,
                              void* d_out, int out_size, void* d_ws,
                              size_t ws_size, hipStream_t stream)
{
    const float* x  = (const float*)d_in[0];
    const float* W1 = (const float*)d_in[1];
    const float* W2 = (const float*)d_in[2];
    const float* a  = (const float*)d_in[3];
    const int* src  = (const int*)d_in[4];
    const int* dst  = (const int*)d_in[5];
    const int N = in_sizes[0] / F_IN;   // 50000
    const int E = in_sizes[4];          // 800000

    float* ws      = (float*)d_ws;
    float* h       = ws;                          // N*64
    float* sdst    = h + (size_t)N * F_OUT;       // N
    float* ssrc    = sdst + N;                    // N
    float* w1t     = ssrc + N;                    // 16384
    float* w2t     = w1t + F_IN * F_OUT;          // 4096
    int*   cnt     = (int*)(w2t + F_OUT * F_OUT); // N
    int*   cursor  = cnt + N;                     // N
    int*   offs    = cursor + N;                  // N
    int*   ssorted = offs + N;                    // E

    hipMemsetAsync(cnt, 0, sizeof(int) * 2 * (size_t)N, stream);

    const int blocksE = (E + 255) / 256;
    prep_hist_kernel<<<blocksE, 256, 0, stream>>>(W1, W2, dst, w1t, w2t, cnt, E);
    mlp_kernel<<<(N + 63) / 64, 256, 0, stream>>>(x, w1t, w2t, a, h, sdst,
                                                  ssrc, N);
    scan_kernel<<<1, 1024, 0, stream>>>(cnt, offs, N);
    scatter_kernel<<<blocksE, 256, 0, stream>>>(src, dst, offs, cursor,
                                                ssorted, E);
    aggregate_kernel<<<(N + 3) / 4, 256, 0, stream>>>(h, sdst, ssrc, offs, cnt,
                                                      ssorted, (float*)d_out, N);
}

// Round 3
// 211.978 us; speedup vs baseline: 1.8564x; 1.2600x over previous
//
#include <hip/hip_runtime.h>
#include <math.h>

#define F_IN 256
#define F_OUT 64
#define NEG_SLOPE 0.01f
#define NB1 128   // coarse-pass blocks

// ---------------------------------------------------------------------------
// K0: transpose W1 (64x256 -> k-major 256x64) and W2 (64x64 -> j-major).
// ---------------------------------------------------------------------------
__global__ void prep_w_kernel(const float* __restrict__ W1,
                              const float* __restrict__ W2,
                              float* __restrict__ w1t,
                              float* __restrict__ w2t)
{
    int idx = blockIdx.x * blockDim.x + threadIdx.x;
    if (idx < F_IN * F_OUT) {
        int k = idx >> 6, f = idx & 63;
        w1t[idx] = W1[f * F_IN + k];
    }
    if (idx < F_OUT * F_OUT) {
        int j = idx >> 6, f = idx & 63;
        w2t[idx] = W2[f * F_OUT + j];
    }
}

// ---------------------------------------------------------------------------
// K1: fused MLP. Block = 256 threads = 64 nodes (lane) x 4 feature-quarters.
// 16 accumulators/thread -> no spill (R1 lesson: 128 accs spilled, 126us).
// ---------------------------------------------------------------------------
__global__ __launch_bounds__(256)
void mlp_kernel(const float* __restrict__ x,
                const float* __restrict__ w1t,
                const float* __restrict__ w2t,
                const float* __restrict__ a,
                float* __restrict__ h,
                float* __restrict__ sdst,
                float* __restrict__ ssrc, int N)
{
    __shared__ float zh[64][65];
    __shared__ float sred[8][64];
    const int tid = threadIdx.x;
    const int lane = tid & 63;
    const int wq = __builtin_amdgcn_readfirstlane(tid >> 6);
    const int node0 = blockIdx.x * 64;
    const int nc = min(node0 + lane, N - 1);
    const float4* __restrict__ xrow = (const float4*)(x + (size_t)nc * F_IN);

    float acc[16];
#pragma unroll
    for (int f = 0; f < 16; f++) acc[f] = 0.f;
    const float* __restrict__ w1p = w1t + wq * 16;
    for (int k4 = 0; k4 < F_IN / 4; k4++) {
        float4 xv = xrow[k4];
        float xs[4] = {xv.x, xv.y, xv.z, xv.w};
#pragma unroll
        for (int kk = 0; kk < 4; kk++) {
            const float4* __restrict__ wrow =
                (const float4*)(w1p + (k4 * 4 + kk) * F_OUT);
            float xk = xs[kk];
#pragma unroll
            for (int fq = 0; fq < 4; fq++) {
                float4 w = wrow[fq];
                acc[4 * fq + 0] = fmaf(xk, w.x, acc[4 * fq + 0]);
                acc[4 * fq + 1] = fmaf(xk, w.y, acc[4 * fq + 1]);
                acc[4 * fq + 2] = fmaf(xk, w.z, acc[4 * fq + 2]);
                acc[4 * fq + 3] = fmaf(xk, w.w, acc[4 * fq + 3]);
            }
        }
    }
#pragma unroll
    for (int f = 0; f < 16; f++) zh[lane][wq * 16 + f] = fmaxf(acc[f], 0.f);
    __syncthreads();

    float hacc[16];
#pragma unroll
    for (int f = 0; f < 16; f++) hacc[f] = 0.f;
    const float* __restrict__ w2p = w2t + wq * 16;
#pragma unroll 8
    for (int j = 0; j < F_OUT; j++) {
        float zj = zh[lane][j];
        const float4* __restrict__ wrow = (const float4*)(w2p + j * F_OUT);
#pragma unroll
        for (int fq = 0; fq < 4; fq++) {
            float4 w = wrow[fq];
            hacc[4 * fq + 0] = fmaf(zj, w.x, hacc[4 * fq + 0]);
            hacc[4 * fq + 1] = fmaf(zj, w.y, hacc[4 * fq + 1]);
            hacc[4 * fq + 2] = fmaf(zj, w.z, hacc[4 * fq + 2]);
            hacc[4 * fq + 3] = fmaf(zj, w.w, hacc[4 * fq + 3]);
        }
    }
    __syncthreads();

    float sd = 0.f, ss = 0.f;
#pragma unroll
    for (int f = 0; f < 16; f++) {
        float hf = fmaxf(hacc[f], 0.f);
        zh[lane][wq * 16 + f] = hf;
        sd = fmaf(hf, a[wq * 16 + f], sd);
        ss = fmaf(hf, a[F_OUT + wq * 16 + f], ss);
    }
    sred[wq][lane] = sd;
    sred[4 + wq][lane] = ss;
    __syncthreads();

    if (tid < 64) {
        int node = node0 + lane;
        if (node < N) {
            sdst[node] = sred[0][lane] + sred[1][lane] + sred[2][lane] + sred[3][lane];
            ssrc[node] = sred[4][lane] + sred[5][lane] + sred[6][lane] + sred[7][lane];
        }
    }
#pragma unroll
    for (int i = 0; i < 4; i++) {
        int idx = tid + 256 * i;
        int nn = idx >> 4;
        int fc = (idx & 15) << 2;
        if (node0 + nn < N) {
            float4 v = make_float4(zh[nn][fc], zh[nn][fc + 1],
                                   zh[nn][fc + 2], zh[nn][fc + 3]);
            *(float4*)(h + (size_t)(node0 + nn) * F_OUT + fc) = v;
        }
    }
}

// ---------------------------------------------------------------------------
// K2: coarse histogram — per-block LDS 256-bin hist of dst>>8; NO global
// atomics (R2 lesson: 800k scattered global atomics = 55MB HBM RMW = 55us).
// ---------------------------------------------------------------------------
__global__ __launch_bounds__(256)
void hist1_kernel(const int* __restrict__ dst, int* __restrict__ blockhist,
                  int E, int chunk)
{
    __shared__ int lh[256];
    const int tid = threadIdx.x;
    lh[tid] = 0;
    __syncthreads();
    const int beg = blockIdx.x * chunk;
    const int end = min(E, beg + chunk);
    for (int i = beg + tid; i < end; i += 256)
        atomicAdd(&lh[((unsigned)dst[i]) >> 8], 1);
    __syncthreads();
    blockhist[tid * NB1 + blockIdx.x] = lh[tid];
}

// ---------------------------------------------------------------------------
// K3: exclusive scan (generic, multi-chunk single block).
// ---------------------------------------------------------------------------
__global__ __launch_bounds__(1024)
void scan_kernel(const int* __restrict__ cnt, int* __restrict__ offs, int N)
{
    __shared__ int wsum[16];
    const int tid = threadIdx.x;
    const int lane = tid & 63;
    const int wid = tid >> 6;
    int carry = 0;
    for (int base = 0; base < N; base += 4096) {
        int i0 = base + tid * 4;
        int v0 = 0, v1 = 0, v2 = 0, v3 = 0;
        if (i0 + 3 < N) {
            int4 v = *(const int4*)(cnt + i0);
            v0 = v.x; v1 = v.y; v2 = v.z; v3 = v.w;
        } else {
            if (i0 < N)     v0 = cnt[i0];
            if (i0 + 1 < N) v1 = cnt[i0 + 1];
            if (i0 + 2 < N) v2 = cnt[i0 + 2];
            if (i0 + 3 < N) v3 = cnt[i0 + 3];
        }
        int tsum = v0 + v1 + v2 + v3;
        int s = tsum;
#pragma unroll
        for (int d = 1; d < 64; d <<= 1) {
            int t = __shfl_up(s, d);
            if (lane >= d) s += t;
        }
        if (lane == 63) wsum[wid] = s;
        __syncthreads();
        if (wid == 0 && lane < 16) {
            int w = wsum[lane];
#pragma unroll
            for (int d = 1; d < 16; d <<= 1) {
                int t = __shfl_up(w, d);
                if (lane >= d) w += t;
            }
            wsum[lane] = w;
        }
        __syncthreads();
        int excl = carry + (wid ? wsum[wid - 1] : 0) + (s - tsum);
        if (i0 < N)     offs[i0]     = excl;
        if (i0 + 1 < N) offs[i0 + 1] = excl + v0;
        if (i0 + 2 < N) offs[i0 + 2] = excl + v0 + v1;
        if (i0 + 3 < N) offs[i0 + 3] = excl + v0 + v1 + v2;
        carry += wsum[15];
        __syncthreads();
    }
}

// ---------------------------------------------------------------------------
// K4: coarse scatter — LDS-atomic ranks + pre-scanned bases; packs
// (dst low byte)<<16 | src into one int (both < 2^16). No global atomics.
// ---------------------------------------------------------------------------
__global__ __launch_bounds__(256)
void scatter1_kernel(const int* __restrict__ src, const int* __restrict__ dst,
                     const int* __restrict__ scanned, int* __restrict__ edata,
                     int E, int chunk)
{
    __shared__ int basebin[256];
    __shared__ int cur[256];
    const int tid = threadIdx.x;
    basebin[tid] = scanned[tid * NB1 + blockIdx.x];
    cur[tid] = 0;
    __syncthreads();
    const int beg = blockIdx.x * chunk;
    const int end = min(E, beg + chunk);
    for (int i = beg + tid; i < end; i += 256) {
        int d = dst[i];
        int s = src[i];
        int bin = ((unsigned)d) >> 8;
        int r = atomicAdd(&cur[bin], 1);
        edata[basebin[bin] + r] = ((d & 0xFF) << 16) | s;
    }
}

// ---------------------------------------------------------------------------
// K5: fine counting sort within each coarse bucket (256 dst values).
// Emits ssorted, cnt[d], offs[d]. No global atomics.
// ---------------------------------------------------------------------------
__global__ __launch_bounds__(256)
void bucket_sort_kernel(const int* __restrict__ scanned,
                        const int* __restrict__ edata,
                        int* __restrict__ ssorted,
                        int* __restrict__ cnt, int* __restrict__ offs,
                        int E, int N)
{
    __shared__ int hist[256];
    __shared__ int excl[256];
    const int tid = threadIdx.x;
    const int lane = tid & 63;
    const int cb = blockIdx.x;
    const int base = scanned[cb * NB1];
    const int endp = (cb + 1 < 256) ? scanned[(cb + 1) * NB1] : E;

    hist[tid] = 0;
    __syncthreads();
    for (int i = base + tid; i < endp; i += 256)
        atomicAdd(&hist[((unsigned)edata[i]) >> 16], 1);
    __syncthreads();

    if (tid < 64) {   // wave 0 scans 256 bins, 4/lane
        int v0 = hist[lane * 4], v1 = hist[lane * 4 + 1];
        int v2 = hist[lane * 4 + 2], v3 = hist[lane * 4 + 3];
        int ts = v0 + v1 + v2 + v3;
        int s = ts;
#pragma unroll
        for (int d = 1; d < 64; d <<= 1) {
            int t = __shfl_up(s, d);
            if (lane >= d) s += t;
        }
        int e = s - ts;
        excl[lane * 4] = e;
        excl[lane * 4 + 1] = e + v0;
        excl[lane * 4 + 2] = e + v0 + v1;
        excl[lane * 4 + 3] = e + v0 + v1 + v2;
    }
    __syncthreads();

    int d = cb * 256 + tid;
    if (d < N) {
        cnt[d] = hist[tid];
        offs[d] = base + excl[tid];
    }
    __syncthreads();

    for (int i = base + tid; i < endp; i += 256) {
        int pack = edata[i];
        int low = ((unsigned)pack) >> 16;
        int r = atomicAdd(&excl[low], 1);
        ssorted[base + r] = pack & 0xFFFF;
    }
}

// ---------------------------------------------------------------------------
// K6: per-dst-node online-softmax aggregation. One wave per node; lane = f.
// ---------------------------------------------------------------------------
__global__ __launch_bounds__(256)
void aggregate_kernel(const float* __restrict__ h,
                      const float* __restrict__ sdst,
                      const float* __restrict__ ssrc,
                      const int* __restrict__ offs,
                      const int* __restrict__ cnt,
                      const int* __restrict__ ssorted,
                      float* __restrict__ out, int N)
{
    __shared__ float w_sh[4][64];
    __shared__ int s_sh[4][64];
    const int lane = threadIdx.x & 63;
    const int wid = threadIdx.x >> 6;
    const int d = blockIdx.x * 4 + wid;
    if (d >= N) return;

    const int off = offs[d];
    const int deg = cnt[d];
    const float sdd = sdst[d];
    float M = -INFINITY, S = 0.f, res = 0.f;

    for (int cb = 0; cb < deg; cb += 64) {
        int ce = min(64, deg - cb);
        float score = -INFINITY;
        int s = 0;
        if (lane < ce) {
            s = ssorted[off + cb + lane];
            float sc = sdd + ssrc[s];
            score = sc > 0.f ? sc : NEG_SLOPE * sc;
        }
        float mc = score;
#pragma unroll
        for (int dd = 32; dd > 0; dd >>= 1)
            mc = fmaxf(mc, __shfl_xor(mc, dd));
        float newM = fmaxf(M, mc);
        float scale = __expf(M - newM);
        float w = (lane < ce) ? __expf(score - newM) : 0.f;
        w_sh[wid][lane] = w;
        s_sh[wid][lane] = s;
        float csum = w;
#pragma unroll
        for (int dd = 32; dd > 0; dd >>= 1)
            csum += __shfl_xor(csum, dd);
        res *= scale;
        S = S * scale + csum;
        __builtin_amdgcn_wave_barrier();
        for (int e = 0; e < ce; e++) {
            float we = w_sh[wid][e];
            int se = s_sh[wid][e];
            res = fmaf(we, h[(size_t)se * F_OUT + lane], res);
        }
        __builtin_amdgcn_wave_barrier();
        M = newM;
    }

    float hf = h[(size_t)d * F_OUT + lane];
    float r = (S > 0.f) ? (hf - res / S) : hf;
    out[(size_t)d * F_OUT + lane] = r > 0.f ? r : 0.f;
}

// ---------------------------------------------------------------------------
extern "C" void kernel_launch(void* const* d_in, const int* in_sizes, int n_in,
                              void* d_out, int out_size, void* d_ws,
                              size_t ws_size, hipStream_t stream)
{
    const float* x  = (const float*)d_in[0];
    const float* W1 = (const float*)d_in[1];
    const float* W2 = (const float*)d_in[2];
    const float* a  = (const float*)d_in[3];
    const int* src  = (const int*)d_in[4];
    const int* dst  = (const int*)d_in[5];
    const int N = in_sizes[0] / F_IN;   // 50000
    const int E = in_sizes[4];          // 800000

    float* ws        = (float*)d_ws;
    float* h         = ws;                            // N*64
    float* sdst      = h + (size_t)N * F_OUT;         // N
    float* ssrc      = sdst + N;                      // N
    float* w1t       = ssrc + N;                      // 16384
    float* w2t       = w1t + F_IN * F_OUT;            // 4096
    int*   cnt       = (int*)(w2t + F_OUT * F_OUT);   // N
    int*   offs      = cnt + N;                       // N
    int*   blockhist = offs + N;                      // 256*NB1
    int*   scanned   = blockhist + 256 * NB1;         // 256*NB1
    int*   edata     = scanned + 256 * NB1;           // E
    int*   ssorted   = edata + E;                     // E

    const int chunk = (E + NB1 - 1) / NB1;
    const int nbc = (N + 255) >> 8;    // coarse buckets

    prep_w_kernel<<<(F_IN * F_OUT + 255) / 256, 256, 0, stream>>>(W1, W2, w1t, w2t);
    mlp_kernel<<<(N + 63) / 64, 256, 0, stream>>>(x, w1t, w2t, a, h, sdst, ssrc, N);
    hist1_kernel<<<NB1, 256, 0, stream>>>(dst, blockhist, E, chunk);
    scan_kernel<<<1, 1024, 0, stream>>>(blockhist, scanned, 256 * NB1);
    scatter1_kernel<<<NB1, 256, 0, stream>>>(src, dst, scanned, edata, E, chunk);
    bucket_sort_kernel<<<nbc, 256, 0, stream>>>(scanned, edata, ssorted, cnt, offs, E, N);
    aggregate_kernel<<<(N + 3) / 4, 256, 0, stream>>>(h, sdst, ssrc, offs, cnt,
                                                      ssorted, (float*)d_out, N);
}

// Round 4
// 203.872 us; speedup vs baseline: 1.9302x; 1.0398x over previous
//
#include <hip/hip_runtime.h>
#include <math.h>

#define F_IN 256
#define F_OUT 64
#define NEG_SLOPE 0.01f
#define NB1 128   // coarse-pass blocks

typedef unsigned short ushort8_t __attribute__((ext_vector_type(8)));

__device__ inline unsigned short f2bf(float f) {   // RNE, inputs are relu'd (>=0)
    unsigned u = __float_as_uint(f);
    u += 0x7FFF + ((u >> 16) & 1);
    return (unsigned short)(u >> 16);
}
__device__ inline float bf2f(unsigned short u) {
    return __uint_as_float(((unsigned)u) << 16);
}

// ---------------------------------------------------------------------------
// K0: transpose W1 (64x256 -> k-major 256x64) and W2 (64x64 -> j-major).
// ---------------------------------------------------------------------------
__global__ void prep_w_kernel(const float* __restrict__ W1,
                              const float* __restrict__ W2,
                              float* __restrict__ w1t,
                              float* __restrict__ w2t)
{
    int idx = blockIdx.x * blockDim.x + threadIdx.x;
    if (idx < F_IN * F_OUT) {
        int k = idx >> 6, f = idx & 63;
        w1t[idx] = W1[f * F_IN + k];
    }
    if (idx < F_OUT * F_OUT) {
        int j = idx >> 6, f = idx & 63;
        w2t[idx] = W2[f * F_OUT + j];
    }
}

// ---------------------------------------------------------------------------
// K1: fused MLP. Block = 256 = 64 nodes (lane) x 4 feature-quarters (wave).
// R3 lesson: weights scalarized fine (VGPR=16/SGPR=96) but ONE x-load in
// flight per wave at 3 waves/SIMD = latency-bound (VALUBusy 27%). Fix:
// 16-k groups with explicit next-group prefetch (4 float4 in flight).
// h stored as bf16 (halves aggregate gather traffic; threshold 2.28 >> drift).
// ---------------------------------------------------------------------------
__global__ __launch_bounds__(256)
void mlp_kernel(const float* __restrict__ x,
                const float* __restrict__ w1t,
                const float* __restrict__ w2t,
                const float* __restrict__ a,
                unsigned short* __restrict__ hb,
                float* __restrict__ sdst,
                float* __restrict__ ssrc, int N)
{
    __shared__ float zh[64][65];
    __shared__ float sred[8][64];
    const int tid = threadIdx.x;
    const int lane = tid & 63;
    const int wq = __builtin_amdgcn_readfirstlane(tid >> 6);
    const int node0 = blockIdx.x * 64;
    const int nc = min(node0 + lane, N - 1);
    const float4* __restrict__ xrow = (const float4*)(x + (size_t)nc * F_IN);

    float acc[16];
#pragma unroll
    for (int f = 0; f < 16; f++) acc[f] = 0.f;
    const float* __restrict__ w1p = w1t + wq * 16;

    float4 xc[4];
#pragma unroll
    for (int i = 0; i < 4; i++) xc[i] = xrow[i];

    for (int g = 0; g < 16; g++) {
        float4 xn[4];
        const int gn = (g + 1) & 15;          // wrap: last prefetch is harmless
#pragma unroll
        for (int i = 0; i < 4; i++) xn[i] = xrow[gn * 4 + i];
        float xs[16];
#pragma unroll
        for (int i = 0; i < 4; i++) {
            xs[4 * i + 0] = xc[i].x; xs[4 * i + 1] = xc[i].y;
            xs[4 * i + 2] = xc[i].z; xs[4 * i + 3] = xc[i].w;
        }
#pragma unroll
        for (int kk = 0; kk < 16; kk++) {
            const float4* __restrict__ wrow =
                (const float4*)(w1p + (g * 16 + kk) * F_OUT);
            float xk = xs[kk];
#pragma unroll
            for (int fq = 0; fq < 4; fq++) {
                float4 w = wrow[fq];
                acc[4 * fq + 0] = fmaf(xk, w.x, acc[4 * fq + 0]);
                acc[4 * fq + 1] = fmaf(xk, w.y, acc[4 * fq + 1]);
                acc[4 * fq + 2] = fmaf(xk, w.z, acc[4 * fq + 2]);
                acc[4 * fq + 3] = fmaf(xk, w.w, acc[4 * fq + 3]);
            }
        }
#pragma unroll
        for (int i = 0; i < 4; i++) xc[i] = xn[i];
    }
#pragma unroll
    for (int f = 0; f < 16; f++) zh[lane][wq * 16 + f] = fmaxf(acc[f], 0.f);
    __syncthreads();

    float hacc[16];
#pragma unroll
    for (int f = 0; f < 16; f++) hacc[f] = 0.f;
    const float* __restrict__ w2p = w2t + wq * 16;
#pragma unroll 8
    for (int j = 0; j < F_OUT; j++) {
        float zj = zh[lane][j];
        const float4* __restrict__ wrow = (const float4*)(w2p + j * F_OUT);
#pragma unroll
        for (int fq = 0; fq < 4; fq++) {
            float4 w = wrow[fq];
            hacc[4 * fq + 0] = fmaf(zj, w.x, hacc[4 * fq + 0]);
            hacc[4 * fq + 1] = fmaf(zj, w.y, hacc[4 * fq + 1]);
            hacc[4 * fq + 2] = fmaf(zj, w.z, hacc[4 * fq + 2]);
            hacc[4 * fq + 3] = fmaf(zj, w.w, hacc[4 * fq + 3]);
        }
    }
    __syncthreads();

    float sd = 0.f, ss = 0.f;
#pragma unroll
    for (int f = 0; f < 16; f++) {
        float hf = fmaxf(hacc[f], 0.f);
        zh[lane][wq * 16 + f] = hf;
        sd = fmaf(hf, a[wq * 16 + f], sd);
        ss = fmaf(hf, a[F_OUT + wq * 16 + f], ss);
    }
    sred[wq][lane] = sd;
    sred[4 + wq][lane] = ss;
    __syncthreads();

    if (tid < 64) {
        int node = node0 + lane;
        if (node < N) {
            sdst[node] = sred[0][lane] + sred[1][lane] + sred[2][lane] + sred[3][lane];
            ssrc[node] = sred[4][lane] + sred[5][lane] + sred[6][lane] + sred[7][lane];
        }
    }
    // bf16 h store: 512 chunks of 8; 16B per store, coalesced within groups.
#pragma unroll
    for (int i = 0; i < 2; i++) {
        int idx = tid + 256 * i;
        int nn = idx >> 3;
        int c0 = (idx & 7) * 8;
        if (node0 + nn < N) {
            ushort8_t v;
#pragma unroll
            for (int c = 0; c < 8; c++) v[c] = f2bf(zh[nn][c0 + c]);
            *(ushort8_t*)(hb + (size_t)(node0 + nn) * F_OUT + c0) = v;
        }
    }
}

// ---------------------------------------------------------------------------
// K2: coarse histogram — per-block LDS 256-bin hist of dst>>8 (no global
// atomics; R2 lesson: 800k global atomics = 55us).
// ---------------------------------------------------------------------------
__global__ __launch_bounds__(256)
void hist1_kernel(const int* __restrict__ dst, int* __restrict__ blockhist,
                  int E, int chunk)
{
    __shared__ int lh[256];
    const int tid = threadIdx.x;
    lh[tid] = 0;
    __syncthreads();
    const int beg = blockIdx.x * chunk;
    const int end = min(E, beg + chunk);
    for (int i = beg + tid; i < end; i += 256)
        atomicAdd(&lh[((unsigned)dst[i]) >> 8], 1);
    __syncthreads();
    blockhist[tid * NB1 + blockIdx.x] = lh[tid];
}

// ---------------------------------------------------------------------------
// K3: one-pass exclusive scan of exactly 32768 ints (1024 thr x 32 each).
// ---------------------------------------------------------------------------
__global__ __launch_bounds__(1024)
void scan32k_kernel(const int* __restrict__ in, int* __restrict__ out)
{
    __shared__ int wsum[16];
    const int tid = threadIdx.x, lane = tid & 63, wid = tid >> 6;
    int v[32];
    const int4* p = (const int4*)(in + tid * 32);
#pragma unroll
    for (int i = 0; i < 8; i++) {
        int4 q = p[i];
        v[4 * i] = q.x; v[4 * i + 1] = q.y; v[4 * i + 2] = q.z; v[4 * i + 3] = q.w;
    }
    int tot = 0;
#pragma unroll
    for (int i = 0; i < 32; i++) { int t = v[i]; v[i] = tot; tot += t; }
    int s = tot;
#pragma unroll
    for (int d = 1; d < 64; d <<= 1) {
        int t = __shfl_up(s, d);
        if (lane >= d) s += t;
    }
    if (lane == 63) wsum[wid] = s;
    __syncthreads();
    if (wid == 0 && lane < 16) {
        int w = wsum[lane];
#pragma unroll
        for (int d = 1; d < 16; d <<= 1) {
            int t = __shfl_up(w, d);
            if (lane >= d) w += t;
        }
        wsum[lane] = w;
    }
    __syncthreads();
    const int base = (wid ? wsum[wid - 1] : 0) + (s - tot);
    int4* o = (int4*)(out + tid * 32);
#pragma unroll
    for (int i = 0; i < 8; i++) {
        int4 r;
        r.x = base + v[4 * i];     r.y = base + v[4 * i + 1];
        r.z = base + v[4 * i + 2]; r.w = base + v[4 * i + 3];
        o[i] = r;
    }
}

// ---------------------------------------------------------------------------
// K4: coarse scatter — LDS-atomic ranks + pre-scanned bases; packs
// (dst low byte)<<16 | src (src < 2^16). No global atomics.
// ---------------------------------------------------------------------------
__global__ __launch_bounds__(256)
void scatter1_kernel(const int* __restrict__ src, const int* __restrict__ dst,
                     const int* __restrict__ scanned, int* __restrict__ edata,
                     int E, int chunk)
{
    __shared__ int basebin[256];
    __shared__ int cur[256];
    const int tid = threadIdx.x;
    basebin[tid] = scanned[tid * NB1 + blockIdx.x];
    cur[tid] = 0;
    __syncthreads();
    const int beg = blockIdx.x * chunk;
    const int end = min(E, beg + chunk);
    for (int i = beg + tid; i < end; i += 256) {
        int d = dst[i];
        int s = src[i];
        int bin = ((unsigned)d) >> 8;
        int r = atomicAdd(&cur[bin], 1);
        edata[basebin[bin] + r] = ((d & 0xFF) << 16) | s;
    }
}

// ---------------------------------------------------------------------------
// K5: fine counting sort within each coarse bucket (256 dst values).
// ---------------------------------------------------------------------------
__global__ __launch_bounds__(256)
void bucket_sort_kernel(const int* __restrict__ scanned,
                        const int* __restrict__ edata,
                        int* __restrict__ ssorted,
                        int* __restrict__ cnt, int* __restrict__ offs,
                        int E, int N)
{
    __shared__ int hist[256];
    __shared__ int excl[256];
    const int tid = threadIdx.x;
    const int lane = tid & 63;
    const int cb = blockIdx.x;
    const int base = scanned[cb * NB1];
    const int endp = (cb + 1 < 256) ? scanned[(cb + 1) * NB1] : E;

    hist[tid] = 0;
    __syncthreads();
    for (int i = base + tid; i < endp; i += 256)
        atomicAdd(&hist[((unsigned)edata[i]) >> 16], 1);
    __syncthreads();

    if (tid < 64) {
        int v0 = hist[lane * 4], v1 = hist[lane * 4 + 1];
        int v2 = hist[lane * 4 + 2], v3 = hist[lane * 4 + 3];
        int ts = v0 + v1 + v2 + v3;
        int s = ts;
#pragma unroll
        for (int d = 1; d < 64; d <<= 1) {
            int t = __shfl_up(s, d);
            if (lane >= d) s += t;
        }
        int e = s - ts;
        excl[lane * 4] = e;
        excl[lane * 4 + 1] = e + v0;
        excl[lane * 4 + 2] = e + v0 + v1;
        excl[lane * 4 + 3] = e + v0 + v1 + v2;
    }
    __syncthreads();

    int d = cb * 256 + tid;
    if (d < N) {
        cnt[d] = hist[tid];
        offs[d] = base + excl[tid];
    }
    __syncthreads();

    for (int i = base + tid; i < endp; i += 256) {
        int pack = edata[i];
        int low = ((unsigned)pack) >> 16;
        int r = atomicAdd(&excl[low], 1);
        ssorted[base + r] = pack & 0xFFFF;
    }
}

// ---------------------------------------------------------------------------
// K6: per-dst-node online-softmax aggregation. One wave per node; lane = f.
// bf16 h gathers (128B/row) + 4 independent chunk accumulators for ILP.
// ---------------------------------------------------------------------------
__global__ __launch_bounds__(256)
void aggregate_kernel(const unsigned short* __restrict__ hb,
                      const float* __restrict__ sdst,
                      const float* __restrict__ ssrc,
                      const int* __restrict__ offs,
                      const int* __restrict__ cnt,
                      const int* __restrict__ ssorted,
                      float* __restrict__ out, int N)
{
    __shared__ float w_sh[4][64];
    __shared__ int s_sh[4][64];
    const int lane = threadIdx.x & 63;
    const int wid = threadIdx.x >> 6;
    const int d = blockIdx.x * 4 + wid;
    if (d >= N) return;

    const int off = offs[d];
    const int deg = cnt[d];
    const float sdd = sdst[d];
    float M = -INFINITY, S = 0.f, res = 0.f;

    for (int cb = 0; cb < deg; cb += 64) {
        int ce = min(64, deg - cb);
        float score = -INFINITY;
        int s = 0;
        if (lane < ce) {
            s = ssorted[off + cb + lane];
            float sc = sdd + ssrc[s];
            score = sc > 0.f ? sc : NEG_SLOPE * sc;
        }
        float mc = score;
#pragma unroll
        for (int dd = 32; dd > 0; dd >>= 1)
            mc = fmaxf(mc, __shfl_xor(mc, dd));
        float newM = fmaxf(M, mc);
        float scale = __expf(M - newM);
        float w = (lane < ce) ? __expf(score - newM) : 0.f;
        w_sh[wid][lane] = w;
        s_sh[wid][lane] = s;
        float csum = w;
#pragma unroll
        for (int dd = 32; dd > 0; dd >>= 1)
            csum += __shfl_xor(csum, dd);
        S = S * scale + csum;
        __builtin_amdgcn_wave_barrier();
        float c0 = 0.f, c1 = 0.f, c2 = 0.f, c3 = 0.f;
        int e = 0;
        for (; e + 4 <= ce; e += 4) {
            c0 = fmaf(w_sh[wid][e + 0],
                      bf2f(hb[(size_t)s_sh[wid][e + 0] * F_OUT + lane]), c0);
            c1 = fmaf(w_sh[wid][e + 1],
                      bf2f(hb[(size_t)s_sh[wid][e + 1] * F_OUT + lane]), c1);
            c2 = fmaf(w_sh[wid][e + 2],
                      bf2f(hb[(size_t)s_sh[wid][e + 2] * F_OUT + lane]), c2);
            c3 = fmaf(w_sh[wid][e + 3],
                      bf2f(hb[(size_t)s_sh[wid][e + 3] * F_OUT + lane]), c3);
        }
        for (; e < ce; e++)
            c0 = fmaf(w_sh[wid][e],
                      bf2f(hb[(size_t)s_sh[wid][e] * F_OUT + lane]), c0);
        res = res * scale + ((c0 + c1) + (c2 + c3));
        __builtin_amdgcn_wave_barrier();
        M = newM;
    }

    float hf = bf2f(hb[(size_t)d * F_OUT + lane]);
    float r = (S > 0.f) ? (hf - res / S) : hf;
    out[(size_t)d * F_OUT + lane] = r > 0.f ? r : 0.f;
}

// ---------------------------------------------------------------------------
extern "C" void kernel_launch(void* const* d_in, const int* in_sizes, int n_in,
                              void* d_out, int out_size, void* d_ws,
                              size_t ws_size, hipStream_t stream)
{
    const float* x  = (const float*)d_in[0];
    const float* W1 = (const float*)d_in[1];
    const float* W2 = (const float*)d_in[2];
    const float* a  = (const float*)d_in[3];
    const int* src  = (const int*)d_in[4];
    const int* dst  = (const int*)d_in[5];
    const int N = in_sizes[0] / F_IN;   // 50000
    const int E = in_sizes[4];          // 800000

    float* ws         = (float*)d_ws;
    float* sdst       = ws;                              // N
    float* ssrc       = sdst + N;                        // N
    float* w1t        = ssrc + N;                        // 16384
    float* w2t        = w1t + F_IN * F_OUT;              // 4096
    unsigned short* hb = (unsigned short*)(w2t + F_OUT * F_OUT);  // N*64 u16
    int*   cnt        = (int*)(hb + (size_t)N * F_OUT);  // N
    int*   offs       = cnt + N;                         // N
    int*   blockhist  = offs + N;                        // 256*NB1
    int*   scanned    = blockhist + 256 * NB1;           // 256*NB1
    int*   edata      = scanned + 256 * NB1;             // E
    int*   ssorted    = edata + E;                       // E

    const int chunk = (E + NB1 - 1) / NB1;
    const int nbc = (N + 255) >> 8;

    prep_w_kernel<<<(F_IN * F_OUT + 255) / 256, 256, 0, stream>>>(W1, W2, w1t, w2t);
    mlp_kernel<<<(N + 63) / 64, 256, 0, stream>>>(x, w1t, w2t, a, hb, sdst, ssrc, N);
    hist1_kernel<<<NB1, 256, 0, stream>>>(dst, blockhist, E, chunk);
    scan32k_kernel<<<1, 1024, 0, stream>>>(blockhist, scanned);
    scatter1_kernel<<<NB1, 256, 0, stream>>>(src, dst, scanned, edata, E, chunk);
    bucket_sort_kernel<<<nbc, 256, 0, stream>>>(scanned, edata, ssorted, cnt, offs, E, N);
    aggregate_kernel<<<(N + 3) / 4, 256, 0, stream>>>(hb, sdst, ssrc, offs, cnt,
                                                      ssorted, (float*)d_out, N);
}